// Round 9
// baseline (125.692 us; speedup 1.0000x reference)
//
#include <hip/hip_runtime.h>

typedef float v2f __attribute__((ext_vector_type(2)));

#define BB 8192
#define NN 36
#define INF_ 8
#define HH 8
#define DHH 9
#define GATF 72
#define ACTF 10
#define NTH 320
#define ROWS 288
#define HSTRIDE 12          // h row: {h0..h8, 1.0, ed, pad} = 12 floats, 48B, 16B-aligned
#define HROWS 37            // 36 real + 1 dummy row per head
#define JCOLS 40            // neighbor-list capacity (u16), 80B/row
#define L2E 1.44269504088896f

static __device__ __forceinline__ v2f mk2(float a, float b) { v2f r; r.x = a; r.y = b; return r; }

__global__ __launch_bounds__(NTH, 6) void gnn_kernel(
    const float* __restrict__ x, const int* __restrict__ adj,
    const float* __restrict__ W, const float* __restrict__ a_src,
    const float* __restrict__ a_dst, const float* __restrict__ W_down,
    const float* __restrict__ b_down, const float* __restrict__ W_mu,
    const float* __restrict__ b_mu, float* __restrict__ out)
{
    const int b = blockIdx.x;
    const int tid = threadIdx.x;

    __shared__ float xcs[NN * 9];                              // 1296 B
    __shared__ __align__(16) float hbuf[HH * HROWS * HSTRIDE]; // 14208 B
    __shared__ unsigned short jl[NN * JCOLS];                  // 2880 B (j*12 offsets)
    __shared__ int cnts[NN];                                   // 144 B
    __shared__ int mstar;                                      // block-uniform padded count
    __shared__ float pd[NN * 9];                               // 1296 B
    __shared__ float feat[GATF];                               // 288 B
    __shared__ __align__(16) float wlds[HH * 7 * 12];          // 2688 B
    __shared__ v2f  aid[HH * DHH];                             // 576 B {a_src,a_dst}
    __shared__ float wdlds[GATF];                              // 288 B
    __shared__ float wmulds[GATF * ACTF + 16];                 // 2944 B (padded for o<16 OOB-safe reads)
    __shared__ float bdlds[1];
    __shared__ float bmulds[ACTF];

    // ---- Phase 0: stage inputs + build neighbor lists ----
    const float* xb = x + (size_t)b * (NN * INF_);
    if (tid < NN * INF_) {
        int n = tid >> 3, c = tid & 7;
        float v = xb[tid];
        if (c < 3) xcs[n * 9 + c] = v;
        else if (c > 3) xcs[n * 9 + (c - 1)] = v;
        if (c == 4) feat[NN + n] = (v > 0.f) ? v : 0.01f * v;   // leaky(t) folded here
    }
    {   // neighbor lists: threads 224..259, one row each
        int i0 = tid - 224;
        if (i0 >= 0 && i0 < NN) {
            const int* ar = adj + i0 * NN;
            int cnt = 0;
            for (int j = 0; j < NN; ++j) {
                if (ar[j] > 0) { jl[i0 * JCOLS + cnt] = (unsigned short)(j * HSTRIDE); ++cnt; }
            }
            cnts[i0] = cnt;
        }
    }
    for (int idx = tid; idx < HH * 7 * DHH; idx += NTH) {
        int row = idx / DHH, d = idx - row * DHH;
        wlds[row * 12 + d] = W[idx];
    }
    if (tid < HH * DHH) aid[tid] = mk2(a_src[tid], a_dst[tid]);
    if (tid >= 128 && tid < 128 + GATF) wdlds[tid - 128] = W_down[tid - 128];
    for (int idx = tid; idx < GATF * ACTF; idx += NTH) wmulds[idx] = W_mu[idx];
    if (tid == 0) bdlds[0] = b_down[0];
    if (tid >= 64 && tid < 64 + ACTF) bmulds[tid - 64] = b_mu[tid - 64];
    __syncthreads();

    // ---- Phase 1+2: tid<288: h-row + es(reg) + ed(into row); 288-295: dummy rows;
    //      296-319: pad lists to block-max (and publish mstar) ----
    const int hh = (tid < ROWS) ? (tid / NN) : 0;
    const int i  = (tid < ROWS) ? (tid - hh * NN) : 0;
    float esr = 0.f;
    if (tid < ROWS) {
        const float* xp = xcs + i * 9;
        const float* wp = wlds + hh * 7 * 12;
        float h0=0.f,h1=0.f,h2=0.f,h3=0.f,h4=0.f,h5=0.f,h6=0.f,h7=0.f,h8=0.f;
        #pragma unroll
        for (int k = 0; k < 7; ++k) {
            float xk = xp[k];
            const float* wr = wp + k * 12;
            float4 wa = *reinterpret_cast<const float4*>(wr);
            float4 wb = *reinterpret_cast<const float4*>(wr + 4);
            float  wc = wr[8];
            h0 = fmaf(xk, wa.x, h0); h1 = fmaf(xk, wa.y, h1);
            h2 = fmaf(xk, wa.z, h2); h3 = fmaf(xk, wa.w, h3);
            h4 = fmaf(xk, wb.x, h4); h5 = fmaf(xk, wb.y, h5);
            h6 = fmaf(xk, wb.z, h6); h7 = fmaf(xk, wb.w, h7);
            h8 = fmaf(xk, wc, h8);
        }
        const v2f* ap = aid + hh * DHH;
        v2f sd = mk2(0.f, 0.f);
        sd = __builtin_elementwise_fma(mk2(h0, h0), ap[0], sd);
        sd = __builtin_elementwise_fma(mk2(h1, h1), ap[1], sd);
        sd = __builtin_elementwise_fma(mk2(h2, h2), ap[2], sd);
        sd = __builtin_elementwise_fma(mk2(h3, h3), ap[3], sd);
        sd = __builtin_elementwise_fma(mk2(h4, h4), ap[4], sd);
        sd = __builtin_elementwise_fma(mk2(h5, h5), ap[5], sd);
        sd = __builtin_elementwise_fma(mk2(h6, h6), ap[6], sd);
        sd = __builtin_elementwise_fma(mk2(h7, h7), ap[7], sd);
        sd = __builtin_elementwise_fma(mk2(h8, h8), ap[8], sd);
        esr = sd.x * L2E;
        float edv = sd.y * L2E;
        float* hp = hbuf + (hh * HROWS + i) * HSTRIDE;
        *reinterpret_cast<float4*>(hp)     = make_float4(h0, h1, h2, h3);
        *reinterpret_cast<float4*>(hp + 4) = make_float4(h4, h5, h6, h7);
        *reinterpret_cast<float4*>(hp + 8) = make_float4(h8, 1.0f, edv, 0.f);  // ones col -> ssum; ed embedded
    } else if (tid < 296) {
        int h2 = tid - 288;
        float* hp = hbuf + (h2 * HROWS + NN) * HSTRIDE;       // dummy row j=36
        *reinterpret_cast<float4*>(hp)     = make_float4(0.f, 0.f, 0.f, 0.f);
        *reinterpret_cast<float4*>(hp + 4) = make_float4(0.f, 0.f, 0.f, 0.f);
        *reinterpret_cast<float4*>(hp + 8) = make_float4(0.f, 0.f, -1000000.0f, 0.f);  // ed=-1e6 -> p=0
    } else {
        int m = 0;
        #pragma unroll
        for (int r = 0; r < NN; ++r) m = max(m, cnts[r]);
        int mpad = (m + 3) & ~3;
        if (tid == 296) mstar = mpad;
        for (int r = tid - 296; r < NN; r += 24) {
            int c0 = cnts[r];
            for (int q = c0; q < mpad; ++q)
                jl[r * JCOLS + q] = (unsigned short)(NN * HSTRIDE);  // -> dummy row
        }
    }
    __syncthreads();

    // ---- Phase 3: sparse attention row + PV(+ssum) + ELU + fused down partial ----
    if (tid < ROWS) {
        const float* hb = hbuf + (hh * HROWS) * HSTRIDE;      // head base (16B-aligned: 1776B stride)
        const unsigned short* jrow = jl + i * JCOLS;
        const int mpad = mstar;                                // block-uniform
        float a0=0.f,a1=0.f,a2=0.f,a3=0.f,a4=0.f,a5=0.f,a6=0.f,a7=0.f,a8=0.f,ssum=0.f;

#define ELEM(e_) { \
        const float* hj_ = hb + (e_); \
        float4 hc_ = *reinterpret_cast<const float4*>(hj_ + 8);   /* {h8, 1, ed, pad} */ \
        float s_ = esr + hc_.z; \
        float p_ = __builtin_exp2f(fmaxf(s_, 0.2f * s_)); \
        float4 ha_ = *reinterpret_cast<const float4*>(hj_); \
        float4 hb_ = *reinterpret_cast<const float4*>(hj_ + 4); \
        a0 = fmaf(p_, ha_.x, a0); a1 = fmaf(p_, ha_.y, a1); \
        a2 = fmaf(p_, ha_.z, a2); a3 = fmaf(p_, ha_.w, a3); \
        a4 = fmaf(p_, hb_.x, a4); a5 = fmaf(p_, hb_.y, a5); \
        a6 = fmaf(p_, hb_.z, a6); a7 = fmaf(p_, hb_.w, a7); \
        a8 = fmaf(p_, hc_.x, a8); ssum += p_; }

        for (int q = 0; q < mpad; q += 4) {
            uint2 jq = *reinterpret_cast<const uint2*>(jrow + q);
            int e0 = (int)(jq.x & 0xffffu), e1 = (int)(jq.x >> 16);
            int e2 = (int)(jq.y & 0xffffu), e3 = (int)(jq.y >> 16);
            ELEM(e0); ELEM(e1); ELEM(e2); ELEM(e3);
        }
#undef ELEM

        float inv = 1.0f / ssum;
        const float* wdp = wdlds + hh * DHH;
        float pdown = 0.f;
#define EPI(val, dd_) { \
        float o_ = (val) * inv; \
        o_ = (o_ > 0.f) ? o_ : (__builtin_exp2f(o_ * L2E) - 1.0f); \
        pdown = fmaf(o_, wdp[dd_], pdown); }
        EPI(a0, 0); EPI(a1, 1); EPI(a2, 2); EPI(a3, 3);
        EPI(a4, 4); EPI(a5, 5); EPI(a6, 6); EPI(a7, 7);
        EPI(a8, 8);
#undef EPI
        pd[i * 9 + hh] = pdown;
    }
    __syncthreads();

    // ---- Phase 4: down + leaky (t-half already in feat from phase 0) ----
    if (tid < NN) {
        const float* pp = pd + tid * 9;
        float acc = bdlds[0];
        #pragma unroll
        for (int h = 0; h < HH; ++h) acc += pp[h];
        feat[tid] = (acc > 0.f) ? acc : 0.01f * acc;
    }
    __syncthreads();

    // ---- Phase 5: mu = feat @ W_mu + b_mu, 64 lanes (4 k-chunks per output), shfl-reduce ----
    if (tid < 64) {
        int o = tid >> 2, q = tid & 3;                 // o in 0..15 (>=10 are dummy, padded arrays)
        float accp = (q == 0 && o < ACTF) ? bmulds[o] : 0.f;
        #pragma unroll
        for (int k = 0; k < 18; ++k) {
            int kk = q * 18 + k;
            accp = fmaf(feat[kk], wmulds[kk * ACTF + o], accp);
        }
        accp += __shfl_down(accp, 1);
        accp += __shfl_down(accp, 2);
        if (q == 0 && o < ACTF) out[(size_t)b * ACTF + o] = accp;
    }
}

extern "C" void kernel_launch(void* const* d_in, const int* in_sizes, int n_in,
                              void* d_out, int out_size, void* d_ws, size_t ws_size,
                              hipStream_t stream) {
    const float* x      = (const float*)d_in[0];
    const int*   adj    = (const int*)d_in[1];
    const float* W      = (const float*)d_in[2];
    const float* a_src  = (const float*)d_in[3];
    const float* a_dst  = (const float*)d_in[4];
    const float* W_down = (const float*)d_in[5];
    const float* b_down = (const float*)d_in[6];
    const float* W_mu   = (const float*)d_in[7];
    const float* b_mu   = (const float*)d_in[8];
    float* out = (float*)d_out;

    gnn_kernel<<<BB, NTH, 0, stream>>>(x, adj, W, a_src, a_dst, W_down, b_down, W_mu, b_mu, out);
}

// Round 10
// 123.449 us; speedup vs baseline: 1.0182x; 1.0182x over previous
//
#include <hip/hip_runtime.h>

typedef float v2f __attribute__((ext_vector_type(2)));

#define BB 8192
#define NN 36
#define INF_ 8
#define HH 8
#define DHH 9
#define GATF 72
#define ACTF 10
#define NTH 640            // 10 waves: early rows in waves 0-4, late in 5-9 (branch-uniform)
#define ROWS 288
#define LBASE 320          // late thread range [320, 608)
#define HSTRIDE 12         // h row: {h0..h8, 1.0, pad, pad}, 48B, 16B-aligned
#define L2E 1.44269504088896f
#define MASKNEG -1000000.0f

static __device__ __forceinline__ v2f mk2(float a, float b) { v2f r; r.x = a; r.y = b; return r; }

__global__ __launch_bounds__(NTH, 7) void gnn_kernel(
    const float* __restrict__ x, const int* __restrict__ adj,
    const float* __restrict__ W, const float* __restrict__ a_src,
    const float* __restrict__ a_dst, const float* __restrict__ W_down,
    const float* __restrict__ b_down, const float* __restrict__ W_mu,
    const float* __restrict__ b_mu, float* __restrict__ out)
{
    const int b = blockIdx.x;
    const int tid = threadIdx.x;

    __shared__ float xcs[NN * 9];                          // 1296 B
    __shared__ float ts[NN];                               // 144 B
    __shared__ __align__(16) float hbuf[ROWS * HSTRIDE];   // 13824 B
    __shared__ __align__(16) float edl[ROWS];              // 1152 B
    __shared__ float esl[ROWS];                            // 1152 B
    __shared__ __align__(16) float adjf[NN * NN];          // 5184 B: 0 or MASKNEG
    __shared__ float part[10 * ROWS];                      // 11520 B, slot-major (stride-1 lanes)
    __shared__ float pd[NN * 9];                           // 1296 B
    __shared__ float feat[GATF];                           // 288 B
    __shared__ __align__(16) float wlds[HH * 7 * 12];      // 2688 B
    __shared__ v2f  aid[HH * DHH];                         // 576 B {a_src,a_dst}
    __shared__ float wdlds[GATF];                          // 288 B
    __shared__ float wmulds[GATF * ACTF];                  // 2880 B
    __shared__ float bdlds[1];
    __shared__ float bmulds[ACTF];

    // ---- Phase 0: stage inputs ----
    const float* xb = x + (size_t)b * (NN * INF_);
    if (tid < NN * INF_) {
        int n = tid >> 3, c = tid & 7;
        float v = xb[tid];
        if (c < 3) xcs[n * 9 + c] = v;
        else if (c > 3) xcs[n * 9 + (c - 1)] = v;
        if (c == 4) ts[n] = v;
    }
    {   // adj -> additive float mask; 324 int4 quads on tids 288..611
        int idx = tid - 288;
        if (idx >= 0 && idx < (NN * NN) / 4) {
            int4 a4 = reinterpret_cast<const int4*>(adj)[idx];
            float4 m4;
            m4.x = (a4.x > 0) ? 0.f : MASKNEG;
            m4.y = (a4.y > 0) ? 0.f : MASKNEG;
            m4.z = (a4.z > 0) ? 0.f : MASKNEG;
            m4.w = (a4.w > 0) ? 0.f : MASKNEG;
            *reinterpret_cast<float4*>(adjf + idx * 4) = m4;
        }
    }
    if (tid < HH * 7 * DHH) {
        int row = tid / DHH, d = tid - row * DHH;
        wlds[row * 12 + d] = W[tid];
    }
    { int idx = tid - 504; if (idx >= 0 && idx < HH * DHH) aid[idx] = mk2(a_src[idx], a_dst[idx]); }
    { int idx = tid - 568; if (idx >= 0 && idx < GATF) wdlds[idx] = W_down[idx]; }
    for (int idx = tid; idx < GATF * ACTF; idx += NTH) wmulds[idx] = W_mu[idx];
    if (tid == 636) bdlds[0] = b_down[0];
    { int idx = tid - 612; if (idx >= 0 && idx < ACTF) bmulds[idx] = b_mu[idx]; }
    __syncthreads();

    // ---- roles ----
    const bool early = (tid < ROWS);                       // j 0..15
    const bool late  = (tid >= LBASE) && (tid < LBASE + ROWS);  // j 16..35
    const int r = early ? tid : (late ? tid - LBASE : 0);
    const int hh = r / NN, i = r - hh * NN;

    // ---- Phase 1+2: early threads compute h-row, es, ed ----
    float esr = 0.f;
    if (early) {
        const float* xp = xcs + i * 9;
        const float* wp = wlds + hh * 7 * 12;
        float h0=0.f,h1=0.f,h2=0.f,h3=0.f,h4=0.f,h5=0.f,h6=0.f,h7=0.f,h8=0.f;
        #pragma unroll
        for (int k = 0; k < 7; ++k) {
            float xk = xp[k];
            const float* wr = wp + k * 12;
            float4 wa = *reinterpret_cast<const float4*>(wr);
            float4 wb = *reinterpret_cast<const float4*>(wr + 4);
            float  wc = wr[8];
            h0 = fmaf(xk, wa.x, h0); h1 = fmaf(xk, wa.y, h1);
            h2 = fmaf(xk, wa.z, h2); h3 = fmaf(xk, wa.w, h3);
            h4 = fmaf(xk, wb.x, h4); h5 = fmaf(xk, wb.y, h5);
            h6 = fmaf(xk, wb.z, h6); h7 = fmaf(xk, wb.w, h7);
            h8 = fmaf(xk, wc, h8);
        }
        float* hp = hbuf + r * HSTRIDE;
        *reinterpret_cast<float4*>(hp)     = make_float4(h0, h1, h2, h3);
        *reinterpret_cast<float4*>(hp + 4) = make_float4(h4, h5, h6, h7);
        *reinterpret_cast<v2f*>(hp + 8)    = mk2(h8, 1.0f);   // ones col -> ssum via FMA
        const v2f* ap = aid + hh * DHH;
        v2f sd = mk2(0.f, 0.f);
        sd = __builtin_elementwise_fma(mk2(h0, h0), ap[0], sd);
        sd = __builtin_elementwise_fma(mk2(h1, h1), ap[1], sd);
        sd = __builtin_elementwise_fma(mk2(h2, h2), ap[2], sd);
        sd = __builtin_elementwise_fma(mk2(h3, h3), ap[3], sd);
        sd = __builtin_elementwise_fma(mk2(h4, h4), ap[4], sd);
        sd = __builtin_elementwise_fma(mk2(h5, h5), ap[5], sd);
        sd = __builtin_elementwise_fma(mk2(h6, h6), ap[6], sd);
        sd = __builtin_elementwise_fma(mk2(h7, h7), ap[7], sd);
        sd = __builtin_elementwise_fma(mk2(h8, h8), ap[8], sd);
        esr = sd.x * L2E;
        edl[r] = sd.y * L2E;
        esl[r] = esr;
    }
    __syncthreads();

    // ---- Phase 3a: split attention row; early j 0..15, late j 16..35 ----
    float a0=0.f,a1=0.f,a2=0.f,a3=0.f,a4=0.f,a5=0.f,a6=0.f,a7=0.f,a8=0.f,ssum=0.f;

#define STEP(jj, ee, mm, es_) { \
        float s_ = (es_) + (ee); \
        float e_ = fmaxf(s_, 0.2f * s_) + (mm); \
        float p_ = __builtin_exp2f(e_); \
        const float* hj_ = hrow + (jj) * HSTRIDE; \
        float4 ha_ = *reinterpret_cast<const float4*>(hj_); \
        float4 hb_ = *reinterpret_cast<const float4*>(hj_ + 4); \
        v2f hc_ = *reinterpret_cast<const v2f*>(hj_ + 8); \
        a0 = fmaf(p_, ha_.x, a0); a1 = fmaf(p_, ha_.y, a1); \
        a2 = fmaf(p_, ha_.z, a2); a3 = fmaf(p_, ha_.w, a3); \
        a4 = fmaf(p_, hb_.x, a4); a5 = fmaf(p_, hb_.y, a5); \
        a6 = fmaf(p_, hb_.z, a6); a7 = fmaf(p_, hb_.w, a7); \
        a8 = fmaf(p_, hc_.x, a8); ssum = fmaf(p_, hc_.y, ssum); }

    if (early) {
        const float* hrow = hbuf + (hh * NN) * HSTRIDE;
        const float* edp = edl + hh * NN;
        const float* amr = adjf + i * NN;
        #pragma unroll
        for (int q = 0; q < 4; ++q) {
            float4 e4 = *reinterpret_cast<const float4*>(edp + q * 4);
            float4 m4 = *reinterpret_cast<const float4*>(amr + q * 4);
            STEP(4 * q + 0, e4.x, m4.x, esr);
            STEP(4 * q + 1, e4.y, m4.y, esr);
            STEP(4 * q + 2, e4.z, m4.z, esr);
            STEP(4 * q + 3, e4.w, m4.w, esr);
        }
        part[0 * ROWS + r] = a0; part[1 * ROWS + r] = a1; part[2 * ROWS + r] = a2;
        part[3 * ROWS + r] = a3; part[4 * ROWS + r] = a4; part[5 * ROWS + r] = a5;
        part[6 * ROWS + r] = a6; part[7 * ROWS + r] = a7; part[8 * ROWS + r] = a8;
        part[9 * ROWS + r] = ssum;
    } else if (late) {
        float esru = esl[r];
        const float* hrow = hbuf + (hh * NN) * HSTRIDE;
        const float* edp = edl + hh * NN;
        const float* amr = adjf + i * NN;
        #pragma unroll
        for (int q = 4; q < 9; ++q) {
            float4 e4 = *reinterpret_cast<const float4*>(edp + q * 4);
            float4 m4 = *reinterpret_cast<const float4*>(amr + q * 4);
            STEP(4 * q + 0, e4.x, m4.x, esru);
            STEP(4 * q + 1, e4.y, m4.y, esru);
            STEP(4 * q + 2, e4.z, m4.z, esru);
            STEP(4 * q + 3, e4.w, m4.w, esru);
        }
    }
#undef STEP
    __syncthreads();

    // ---- Phase 3b: late combines partials, normalizes, ELU, down-partial ----
    if (late) {
        a0 += part[0 * ROWS + r]; a1 += part[1 * ROWS + r]; a2 += part[2 * ROWS + r];
        a3 += part[3 * ROWS + r]; a4 += part[4 * ROWS + r]; a5 += part[5 * ROWS + r];
        a6 += part[6 * ROWS + r]; a7 += part[7 * ROWS + r]; a8 += part[8 * ROWS + r];
        ssum += part[9 * ROWS + r];
        float inv = 1.0f / ssum;
        const float* wdp = wdlds + hh * DHH;
        float pdown = 0.f;
#define EPI(val, dd_) { \
        float o_ = (val) * inv; \
        o_ = (o_ > 0.f) ? o_ : (__builtin_exp2f(o_ * L2E) - 1.0f); \
        pdown = fmaf(o_, wdp[dd_], pdown); }
        EPI(a0, 0); EPI(a1, 1); EPI(a2, 2); EPI(a3, 3);
        EPI(a4, 4); EPI(a5, 5); EPI(a6, 6); EPI(a7, 7);
        EPI(a8, 8);
#undef EPI
        pd[i * 9 + hh] = pdown;
    }
    __syncthreads();

    // ---- Phase 4: down + feat = leaky_relu(concat(down, t), 0.01) ----
    if (tid < NN) {
        const float* pp = pd + tid * 9;
        float acc = bdlds[0];
        #pragma unroll
        for (int h = 0; h < HH; ++h) acc += pp[h];
        feat[tid] = (acc > 0.f) ? acc : 0.01f * acc;
    } else if (tid < 2 * NN) {
        float v = ts[tid - NN];
        feat[tid] = (v > 0.f) ? v : 0.01f * v;
    }
    __syncthreads();

    // ---- Phase 5: mu = feat @ W_mu + b_mu ----
    if (tid < ACTF) {
        float acc = bmulds[tid];
        #pragma unroll
        for (int k = 0; k < GATF; ++k) acc = fmaf(feat[k], wmulds[k * ACTF + tid], acc);
        out[(size_t)b * ACTF + tid] = acc;
    }
}

extern "C" void kernel_launch(void* const* d_in, const int* in_sizes, int n_in,
                              void* d_out, int out_size, void* d_ws, size_t ws_size,
                              hipStream_t stream) {
    const float* x      = (const float*)d_in[0];
    const int*   adj    = (const int*)d_in[1];
    const float* W      = (const float*)d_in[2];
    const float* a_src  = (const float*)d_in[3];
    const float* a_dst  = (const float*)d_in[4];
    const float* W_down = (const float*)d_in[5];
    const float* b_down = (const float*)d_in[6];
    const float* W_mu   = (const float*)d_in[7];
    const float* b_mu   = (const float*)d_in[8];
    float* out = (float*)d_out;

    gnn_kernel<<<BB, NTH, 0, stream>>>(x, adj, W, a_src, a_dst, W_down, b_down, W_mu, b_mu, out);
}

// Round 11
// 84.286 us; speedup vs baseline: 1.4912x; 1.4646x over previous
//
#include <hip/hip_runtime.h>

typedef float v2f __attribute__((ext_vector_type(2)));

#define BB 8192
#define NN 36
#define INF_ 8
#define HH 8
#define DHH 9
#define GATF 72
#define ACTF 10
#define NTH 320
#define ROWS 288
#define HSTRIDE 12         // h row: {h0..h8, 1.0, pad, pad}, 48B, 16B-aligned
#define WSTRIDE 12
#define L2E 1.44269504088896f
#define MASKNEG -1000000.0f

static __device__ __forceinline__ v2f mk2(float a, float b) { v2f r; r.x = a; r.y = b; return r; }

__global__ __launch_bounds__(NTH, 6) void gnn_kernel(
    const float* __restrict__ x, const int* __restrict__ adj,
    const float* __restrict__ W, const float* __restrict__ a_src,
    const float* __restrict__ a_dst, const float* __restrict__ W_down,
    const float* __restrict__ b_down, const float* __restrict__ W_mu,
    const float* __restrict__ b_mu, float* __restrict__ out)
{
    const int b0 = blockIdx.x * 2;          // two graphs per block, processed serially
    const int tid = threadIdx.x;

    __shared__ float xcs[2 * NN * 9];                      // 2592 B (both items)
    __shared__ float ts[2 * NN];                           // 288 B
    __shared__ __align__(16) float hbuf[ROWS * HSTRIDE];   // 13824 B (reused per item)
    __shared__ __align__(16) float edl[ROWS];              // 1152 B
    __shared__ __align__(16) float adjf[NN * NN];          // 5184 B: 0 or MASKNEG
    __shared__ float pd[NN * 9];                           // 1296 B
    __shared__ float feat[GATF];                           // 288 B
    __shared__ __align__(16) float wlds[HH * 7 * WSTRIDE]; // 2688 B
    __shared__ v2f  aid[HH * DHH];                         // 576 B {a_src,a_dst}
    __shared__ float wdlds[GATF];                          // 288 B
    __shared__ float wmulds[GATF * ACTF];                  // 2880 B
    __shared__ float bdlds[1];
    __shared__ float bmulds[ACTF];

    // ---- Phase 0: stage inputs for BOTH items + shared weights/adj ----
    {   // x: 576 elements (2 graphs), grid-stride
        const float* xb = x + (size_t)b0 * (NN * INF_);
        for (int idx = tid; idx < 2 * NN * INF_; idx += NTH) {
            int item = idx / (NN * INF_);
            int rem = idx - item * (NN * INF_);
            int n = rem >> 3, c = rem & 7;
            float v = xb[idx];
            float* xc = xcs + item * (NN * 9);
            if (c < 3) xc[n * 9 + c] = v;
            else if (c > 3) xc[n * 9 + (c - 1)] = v;
            if (c == 4) ts[item * NN + n] = v;
        }
    }
    // adj -> additive float mask; 324 int4 quads, grid-stride
    for (int idx = tid; idx < (NN * NN) / 4; idx += NTH) {
        int4 a4 = reinterpret_cast<const int4*>(adj)[idx];
        float4 m4;
        m4.x = (a4.x > 0) ? 0.f : MASKNEG;
        m4.y = (a4.y > 0) ? 0.f : MASKNEG;
        m4.z = (a4.z > 0) ? 0.f : MASKNEG;
        m4.w = (a4.w > 0) ? 0.f : MASKNEG;
        *reinterpret_cast<float4*>(adjf + idx * 4) = m4;
    }
    for (int idx = tid; idx < HH * 7 * DHH; idx += NTH) {
        int row = idx / DHH, d = idx - row * DHH;
        wlds[row * WSTRIDE + d] = W[idx];
    }
    if (tid < HH * DHH) aid[tid] = mk2(a_src[tid], a_dst[tid]);
    if (tid >= 128 && tid < 128 + GATF) wdlds[tid - 128] = W_down[tid - 128];
    for (int idx = tid; idx < GATF * ACTF; idx += NTH) wmulds[idx] = W_mu[idx];
    if (tid == 0) bdlds[0] = b_down[0];
    if (tid >= 64 && tid < 64 + ACTF) bmulds[tid - 64] = b_mu[tid - 64];
    __syncthreads();

    const int hh = (tid < ROWS) ? (tid / NN) : 0;
    const int i  = (tid < ROWS) ? (tid - hh * NN) : 0;

    for (int it = 0; it < 2; ++it) {
        // ---- Phase 1+2: per (h,i) row: h-row, es (reg), ed (LDS) ----
        float esr = 0.f;
        if (tid < ROWS) {
            const float* xp = xcs + it * (NN * 9) + i * 9;
            const float* wp = wlds + hh * 7 * WSTRIDE;
            float h0=0.f,h1=0.f,h2=0.f,h3=0.f,h4=0.f,h5=0.f,h6=0.f,h7=0.f,h8=0.f;
            #pragma unroll
            for (int k = 0; k < 7; ++k) {
                float xk = xp[k];
                const float* wr = wp + k * WSTRIDE;
                float4 wa = *reinterpret_cast<const float4*>(wr);
                float4 wb = *reinterpret_cast<const float4*>(wr + 4);
                float  wc = wr[8];
                h0 = fmaf(xk, wa.x, h0); h1 = fmaf(xk, wa.y, h1);
                h2 = fmaf(xk, wa.z, h2); h3 = fmaf(xk, wa.w, h3);
                h4 = fmaf(xk, wb.x, h4); h5 = fmaf(xk, wb.y, h5);
                h6 = fmaf(xk, wb.z, h6); h7 = fmaf(xk, wb.w, h7);
                h8 = fmaf(xk, wc, h8);
            }
            float* hp = hbuf + (hh * NN + i) * HSTRIDE;
            *reinterpret_cast<float4*>(hp)     = make_float4(h0, h1, h2, h3);
            *reinterpret_cast<float4*>(hp + 4) = make_float4(h4, h5, h6, h7);
            *reinterpret_cast<v2f*>(hp + 8)    = mk2(h8, 1.0f);   // ones col -> ssum via FMA
            const v2f* ap = aid + hh * DHH;
            v2f sd = mk2(0.f, 0.f);
            sd = __builtin_elementwise_fma(mk2(h0, h0), ap[0], sd);
            sd = __builtin_elementwise_fma(mk2(h1, h1), ap[1], sd);
            sd = __builtin_elementwise_fma(mk2(h2, h2), ap[2], sd);
            sd = __builtin_elementwise_fma(mk2(h3, h3), ap[3], sd);
            sd = __builtin_elementwise_fma(mk2(h4, h4), ap[4], sd);
            sd = __builtin_elementwise_fma(mk2(h5, h5), ap[5], sd);
            sd = __builtin_elementwise_fma(mk2(h6, h6), ap[6], sd);
            sd = __builtin_elementwise_fma(mk2(h7, h7), ap[7], sd);
            sd = __builtin_elementwise_fma(mk2(h8, h8), ap[8], sd);
            esr = sd.x * L2E;
            edl[hh * NN + i] = sd.y * L2E;
        }
        __syncthreads();

        // ---- Phase 3: attention row + PV(+ssum) + ELU + fused down partial ----
        if (tid < ROWS) {
            const float* hrow = hbuf + (hh * NN) * HSTRIDE;
            const float* edp = edl + hh * NN;
            const float* amr = adjf + i * NN;
            v2f acc01 = mk2(0.f, 0.f), acc23 = acc01, acc45 = acc01, acc67 = acc01, acc89 = acc01;

#define STEP(jj, ee, mm) { \
            float s_ = esr + (ee); \
            float e_ = fmaxf(s_, 0.2f * s_) + (mm);          /* leaky + additive mask */ \
            float p_ = __builtin_exp2f(e_);                  /* masked -> exact 0 */ \
            const float* hj_ = hrow + (jj) * HSTRIDE; \
            float4 ha_ = *reinterpret_cast<const float4*>(hj_); \
            float4 hb_ = *reinterpret_cast<const float4*>(hj_ + 4); \
            v2f hc_ = *reinterpret_cast<const v2f*>(hj_ + 8); \
            v2f pp_ = mk2(p_, p_); \
            acc01 = __builtin_elementwise_fma(pp_, mk2(ha_.x, ha_.y), acc01); \
            acc23 = __builtin_elementwise_fma(pp_, mk2(ha_.z, ha_.w), acc23); \
            acc45 = __builtin_elementwise_fma(pp_, mk2(hb_.x, hb_.y), acc45); \
            acc67 = __builtin_elementwise_fma(pp_, mk2(hb_.z, hb_.w), acc67); \
            acc89 = __builtin_elementwise_fma(pp_, hc_, acc89); }

            #pragma unroll
            for (int q = 0; q < 9; ++q) {
                float4 e4 = *reinterpret_cast<const float4*>(edp + q * 4);
                float4 m4 = *reinterpret_cast<const float4*>(amr + q * 4);
                STEP(4 * q + 0, e4.x, m4.x);
                STEP(4 * q + 1, e4.y, m4.y);
                STEP(4 * q + 2, e4.z, m4.z);
                STEP(4 * q + 3, e4.w, m4.w);
            }
#undef STEP

            float inv = 1.0f / acc89.y;                       // ssum from ones column
            v2f inv2 = mk2(inv, inv);
            v2f o01 = acc01 * inv2, o23 = acc23 * inv2, o45 = acc45 * inv2, o67 = acc67 * inv2;
            float o8 = acc89.x * inv;
            const float* wdp = wdlds + hh * DHH;
            float pdown = 0.f;
#define EPI(oval, dd_) { \
            float o_ = (oval); \
            o_ = (o_ > 0.f) ? o_ : (__builtin_exp2f(o_ * L2E) - 1.0f); \
            pdown = fmaf(o_, wdp[dd_], pdown); }
            EPI(o01.x, 0); EPI(o01.y, 1); EPI(o23.x, 2); EPI(o23.y, 3);
            EPI(o45.x, 4); EPI(o45.y, 5); EPI(o67.x, 6); EPI(o67.y, 7);
            EPI(o8, 8);
#undef EPI
            pd[i * 9 + hh] = pdown;
        }
        __syncthreads();

        // ---- Phase 4: down + feat = leaky_relu(concat(down, t), 0.01) ----
        if (tid < NN) {
            const float* pp = pd + tid * 9;
            float acc = bdlds[0];
            #pragma unroll
            for (int h = 0; h < HH; ++h) acc += pp[h];
            feat[tid] = (acc > 0.f) ? acc : 0.01f * acc;
        } else if (tid < 2 * NN) {
            float v = ts[it * NN + (tid - NN)];
            feat[tid] = (v > 0.f) ? v : 0.01f * v;
        }
        __syncthreads();

        // ---- Phase 5: mu = feat @ W_mu + b_mu ----
        if (tid < ACTF) {
            float acc = bmulds[tid];
            #pragma unroll
            for (int k = 0; k < GATF; ++k) acc = fmaf(feat[k], wmulds[k * ACTF + tid], acc);
            out[(size_t)(b0 + it) * ACTF + tid] = acc;
        }
        // no barrier needed here: next item's phase-1+2 writes (hbuf/edl) don't
        // alias feat/wmulds; pd/feat reuse is protected by the phase-3/4 barriers.
    }
}

extern "C" void kernel_launch(void* const* d_in, const int* in_sizes, int n_in,
                              void* d_out, int out_size, void* d_ws, size_t ws_size,
                              hipStream_t stream) {
    const float* x      = (const float*)d_in[0];
    const int*   adj    = (const int*)d_in[1];
    const float* W      = (const float*)d_in[2];
    const float* a_src  = (const float*)d_in[3];
    const float* a_dst  = (const float*)d_in[4];
    const float* W_down = (const float*)d_in[5];
    const float* b_down = (const float*)d_in[6];
    const float* W_mu   = (const float*)d_in[7];
    const float* b_mu   = (const float*)d_in[8];
    float* out = (float*)d_out;

    gnn_kernel<<<BB / 2, NTH, 0, stream>>>(x, adj, W, a_src, a_dst, W_down, b_down, W_mu, b_mu, out);
}

// Round 12
// 76.888 us; speedup vs baseline: 1.6347x; 1.0962x over previous
//
#include <hip/hip_runtime.h>

typedef float v2f __attribute__((ext_vector_type(2)));

#define BB 8192
#define NN 36
#define INF_ 8
#define HH 8
#define DHH 9
#define GATF 72
#define ACTF 10
#define NTH 320
#define HSTRIDE 12
#define WSTRIDE 12
#define L2E 1.44269504088896f

__global__ __launch_bounds__(NTH, 6) void gnn_kernel(
    const float* __restrict__ x, const int* __restrict__ adj,
    const float* __restrict__ W, const float* __restrict__ a_src,
    const float* __restrict__ a_dst, const float* __restrict__ W_down,
    const float* __restrict__ b_down, const float* __restrict__ W_mu,
    const float* __restrict__ b_mu, float* __restrict__ out)
{
    const int b = blockIdx.x;
    const int tid = threadIdx.x;

    __shared__ float xcs[NN * 9];                        // xc, stride 9
    __shared__ float ts[NN];                             // t = x[:,:,4]
    __shared__ __align__(16) float hbuf[HH * NN * HSTRIDE];   // 13824 B
    __shared__ __align__(16) float edl[HH * NN];         // ed * log2e
    __shared__ uint2 adjm[NN];                           // row bitmasks
    __shared__ float pd[NN * 9];                         // partial down [i][h]
    __shared__ float feat[GATF];
    __shared__ __align__(16) float wlds[HH * 7 * WSTRIDE];  // W rows 16B-aligned
    __shared__ float aslds[HH * DHH];
    __shared__ float adlds[HH * DHH];
    __shared__ float wdlds[GATF];
    __shared__ float wmulds[GATF * ACTF];
    __shared__ float bdlds[1];
    __shared__ float bmulds[ACTF];

    // ---- Phase 0: stage inputs ----
    const float* xb = x + (size_t)b * (NN * INF_);
    if (tid < NN * INF_) {
        int n = tid >> 3, c = tid & 7;
        float v = xb[tid];
        if (c < 3) xcs[n * 9 + c] = v;
        else if (c > 3) xcs[n * 9 + (c - 1)] = v;
        if (c == 4) ts[n] = v;
    }
    {   // adjacency -> 36 row bitmasks on threads 256..291
        int i0 = tid - 256;
        if (i0 >= 0 && i0 < NN) {
            const int4* ap = reinterpret_cast<const int4*>(adj + i0 * NN);  // 144B rows, 16B-aligned
            unsigned int lo = 0u, hi = 0u;
            #pragma unroll
            for (int q = 0; q < 9; ++q) {
                int4 a4 = ap[q];
                const int base = q * 4;
                if (base + 0 < 32) { lo |= (a4.x > 0 ? 1u << (base + 0) : 0u); } else { hi |= (a4.x > 0 ? 1u << (base - 32) : 0u); }
                if (base + 1 < 32) { lo |= (a4.y > 0 ? 1u << (base + 1) : 0u); } else { hi |= (a4.y > 0 ? 1u << (base + 1 - 32) : 0u); }
                if (base + 2 < 32) { lo |= (a4.z > 0 ? 1u << (base + 2) : 0u); } else { hi |= (a4.z > 0 ? 1u << (base + 2 - 32) : 0u); }
                if (base + 3 < 32) { lo |= (a4.w > 0 ? 1u << (base + 3) : 0u); } else { hi |= (a4.w > 0 ? 1u << (base + 3 - 32) : 0u); }
            }
            adjm[i0] = make_uint2(lo, hi);
        }
    }
    for (int idx = tid; idx < HH * 7 * DHH; idx += NTH) {
        int row = idx / DHH, d = idx - row * DHH;
        wlds[row * WSTRIDE + d] = W[idx];
    }
    if (tid < HH * DHH) { aslds[tid] = a_src[tid]; adlds[tid] = a_dst[tid]; }
    if (tid >= 128 && tid < 128 + GATF) wdlds[tid - 128] = W_down[tid - 128];
    for (int idx = tid; idx < GATF * ACTF; idx += NTH) wmulds[idx] = W_mu[idx];
    if (tid == 0) bdlds[0] = b_down[0];
    if (tid >= 64 && tid < 64 + ACTF) bmulds[tid - 64] = b_mu[tid - 64];
    __syncthreads();

    // ---- Phase 1+2 merged: one thread per (h,i) row computes h-row, es (reg), ed (LDS) ----
    const int hh = (tid < HH * NN) ? (tid / NN) : 0;
    const int i  = (tid < HH * NN) ? (tid - hh * NN) : 0;
    float esr = 0.f;
    if (tid < HH * NN) {
        const float* xp = xcs + i * 9;
        float h0=0.f,h1=0.f,h2=0.f,h3=0.f,h4=0.f,h5=0.f,h6=0.f,h7=0.f,h8=0.f;
        const float* wp = wlds + hh * 7 * WSTRIDE;
        #pragma unroll
        for (int k = 0; k < 7; ++k) {
            float xk = xp[k];
            const float* wr = wp + k * WSTRIDE;
            float4 wa = *reinterpret_cast<const float4*>(wr);
            float4 wb = *reinterpret_cast<const float4*>(wr + 4);
            float  wc = wr[8];
            h0 = fmaf(xk, wa.x, h0); h1 = fmaf(xk, wa.y, h1);
            h2 = fmaf(xk, wa.z, h2); h3 = fmaf(xk, wa.w, h3);
            h4 = fmaf(xk, wb.x, h4); h5 = fmaf(xk, wb.y, h5);
            h6 = fmaf(xk, wb.z, h6); h7 = fmaf(xk, wb.w, h7);
            h8 = fmaf(xk, wc, h8);
        }
        float* hp = hbuf + (hh * NN + i) * HSTRIDE;
        *reinterpret_cast<float4*>(hp)     = make_float4(h0, h1, h2, h3);
        *reinterpret_cast<float4*>(hp + 4) = make_float4(h4, h5, h6, h7);
        hp[8] = h8;
        const float* asp = aslds + hh * DHH;
        const float* adp = adlds + hh * DHH;
        float s = 0.f, dd = 0.f;
        s = fmaf(h0, asp[0], s); dd = fmaf(h0, adp[0], dd);
        s = fmaf(h1, asp[1], s); dd = fmaf(h1, adp[1], dd);
        s = fmaf(h2, asp[2], s); dd = fmaf(h2, adp[2], dd);
        s = fmaf(h3, asp[3], s); dd = fmaf(h3, adp[3], dd);
        s = fmaf(h4, asp[4], s); dd = fmaf(h4, adp[4], dd);
        s = fmaf(h5, asp[5], s); dd = fmaf(h5, adp[5], dd);
        s = fmaf(h6, asp[6], s); dd = fmaf(h6, adp[6], dd);
        s = fmaf(h7, asp[7], s); dd = fmaf(h7, adp[7], dd);
        s = fmaf(h8, asp[8], s); dd = fmaf(h8, adp[8], dd);
        esr = s * L2E;                    // prescaled by log2e
        edl[hh * NN + i] = dd * L2E;      // prescaled by log2e
    }
    __syncthreads();

    // ---- Phase 3: attention row + PV + ELU + fused down partial ----
    if (tid < HH * NN) {
        const uint2 mrow = adjm[i];
        const float* hrow = hbuf + (hh * NN) * HSTRIDE;
        const float* edp = edl + hh * NN;
        v2f acc01 = {0.f, 0.f}, acc23 = {0.f, 0.f}, acc45 = {0.f, 0.f}, acc67 = {0.f, 0.f};
        float acc8 = 0.f, ssum = 0.f;

#define STEP(jj, ee) { \
        float s_ = esr + (ee); \
        float e_ = fmaxf(s_, 0.2f * s_);                 /* leaky (prescaled) */ \
        float p_ = __builtin_exp2f(e_); \
        unsigned bit_ = (((jj) < 32) ? (mrow.x >> (jj)) : (mrow.y >> ((jj) - 32))) & 1u; \
        p_ *= (float)bit_;                               /* mask: exact 0 */ \
        ssum += p_; \
        const float* hj_ = hrow + (jj) * HSTRIDE; \
        float4 ha_ = *reinterpret_cast<const float4*>(hj_); \
        float4 hb_ = *reinterpret_cast<const float4*>(hj_ + 4); \
        float  hc_ = hj_[8]; \
        v2f pp_ = {p_, p_}; \
        v2f h01_ = {ha_.x, ha_.y}, h23_ = {ha_.z, ha_.w}; \
        v2f h45_ = {hb_.x, hb_.y}, h67_ = {hb_.z, hb_.w}; \
        acc01 = __builtin_elementwise_fma(pp_, h01_, acc01); \
        acc23 = __builtin_elementwise_fma(pp_, h23_, acc23); \
        acc45 = __builtin_elementwise_fma(pp_, h45_, acc45); \
        acc67 = __builtin_elementwise_fma(pp_, h67_, acc67); \
        acc8 = fmaf(p_, hc_, acc8); \
    }

        #pragma unroll
        for (int q = 0; q < 9; ++q) {
            float4 e4 = *reinterpret_cast<const float4*>(edp + q * 4);  // broadcast, aligned
            STEP(4 * q + 0, e4.x);
            STEP(4 * q + 1, e4.y);
            STEP(4 * q + 2, e4.z);
            STEP(4 * q + 3, e4.w);
        }
#undef STEP

        float inv = 1.0f / ssum;
        const float* wdp = wdlds + hh * DHH;
        float pdown = 0.f;
#define EPI(val, dd_) { \
        float o_ = (val) * inv; \
        o_ = (o_ > 0.f) ? o_ : (__builtin_exp2f(o_ * L2E) - 1.0f);  /* elu */ \
        pdown = fmaf(o_, wdp[dd_], pdown); \
    }
        EPI(acc01.x, 0); EPI(acc01.y, 1); EPI(acc23.x, 2); EPI(acc23.y, 3);
        EPI(acc45.x, 4); EPI(acc45.y, 5); EPI(acc67.x, 6); EPI(acc67.y, 7);
        EPI(acc8, 8);
#undef EPI
        pd[i * 9 + hh] = pdown;
    }
    __syncthreads();

    // ---- Phase 4: down + feat = leaky_relu(concat(down, t), 0.01) ----
    if (tid < NN) {
        const float* pp = pd + tid * 9;
        float acc = bdlds[0];
        #pragma unroll
        for (int h = 0; h < HH; ++h) acc += pp[h];
        feat[tid] = (acc > 0.f) ? acc : 0.01f * acc;
    } else if (tid < 2 * NN) {
        float v = ts[tid - NN];
        feat[tid] = (v > 0.f) ? v : 0.01f * v;
    }
    __syncthreads();

    // ---- Phase 5: mu = feat @ W_mu + b_mu ----
    if (tid < ACTF) {
        float acc = bmulds[tid];
        #pragma unroll
        for (int k = 0; k < GATF; ++k) acc += feat[k] * wmulds[k * ACTF + tid];
        out[(size_t)b * ACTF + tid] = acc;
    }
}

extern "C" void kernel_launch(void* const* d_in, const int* in_sizes, int n_in,
                              void* d_out, int out_size, void* d_ws, size_t ws_size,
                              hipStream_t stream) {
    const float* x      = (const float*)d_in[0];
    const int*   adj    = (const int*)d_in[1];
    const float* W      = (const float*)d_in[2];
    const float* a_src  = (const float*)d_in[3];
    const float* a_dst  = (const float*)d_in[4];
    const float* W_down = (const float*)d_in[5];
    const float* b_down = (const float*)d_in[6];
    const float* W_mu   = (const float*)d_in[7];
    const float* b_mu   = (const float*)d_in[8];
    float* out = (float*)d_out;

    gnn_kernel<<<BB, NTH, 0, stream>>>(x, adj, W, a_src, a_dst, W_down, b_down, W_mu, b_mu, out);
}